// Round 1
// baseline (14660.368 us; speedup 1.0000x reference)
//
#include <hip/hip_runtime.h>
#include <math.h>

#define N_NODES  100000
#define N_HEDGES 50000
#define N_INC    300000
#define N_GRAPHS 1024
#define D_IN     49
#define D        512
#define NPAD     100096   // 782 * 128
#define KPAD_IN  64

typedef __attribute__((ext_vector_type(8))) short short8;
typedef __attribute__((ext_vector_type(4))) float f32x4;

__device__ inline short f2bf(float f) {
    union { float f; unsigned u; } v; v.f = f;
    unsigned r = v.u + 0x7fffu + ((v.u >> 16) & 1u);
    return (short)(r >> 16);
}

// ---------------- GEMM: C[M,512] = A[M,K](bf16) @ B (given as Bt[512,K] bf16) + bias (+resid) ----------------
// 128x128 tile, 4 waves (2x2), each wave 64x64 via 4x4 of 16x16x32 MFMA.
__global__ __launch_bounds__(256) void gemm_bf16(
    const short* __restrict__ A, const short* __restrict__ Bt,
    const float* __restrict__ bias, const float* __restrict__ resid,
    float* __restrict__ C, int K)
{
    __shared__ short As[128][32];
    __shared__ short Bs[128][32];
    const int tid  = threadIdx.x;
    const int lane = tid & 63;
    const int wave = tid >> 6;
    const int wr = wave >> 1, wc = wave & 1;
    const long row0 = (long)blockIdx.x * 128;
    const int  col0 = blockIdx.y * 128;

    f32x4 acc[4][4];
    for (int m = 0; m < 4; m++)
        for (int n = 0; n < 4; n++)
            acc[m][n] = (f32x4)(0.0f);

    const int sr = tid >> 1;        // staging row 0..127
    const int s0 = (tid & 1) * 2;   // logical 16B slot 0 or 2
    const int sw = (sr >> 1) & 3;   // XOR swizzle for bank-conflict-free ds_read_b128

    const short* aRow = A  + (row0 + sr) * (long)K;
    const short* bRow = Bt + (long)(col0 + sr) * K;

    for (int k0 = 0; k0 < K; k0 += 32) {
        short8 av0 = *(const short8*)(aRow + k0 + s0 * 8);
        short8 av1 = *(const short8*)(aRow + k0 + s0 * 8 + 8);
        short8 bv0 = *(const short8*)(bRow + k0 + s0 * 8);
        short8 bv1 = *(const short8*)(bRow + k0 + s0 * 8 + 8);
        __syncthreads();
        *(short8*)&As[sr][( s0      ^ sw) * 8] = av0;
        *(short8*)&As[sr][((s0 + 1) ^ sw) * 8] = av1;
        *(short8*)&Bs[sr][( s0      ^ sw) * 8] = bv0;
        *(short8*)&Bs[sr][((s0 + 1) ^ sw) * 8] = bv1;
        __syncthreads();
        const int ks = lane >> 4;
        const int rl = lane & 15;
        short8 a[4], b[4];
        for (int m = 0; m < 4; m++) {
            int rr = wr * 64 + m * 16 + rl;
            a[m] = *(const short8*)&As[rr][(ks ^ ((rr >> 1) & 3)) * 8];
        }
        for (int n = 0; n < 4; n++) {
            int rr = wc * 64 + n * 16 + rl;
            b[n] = *(const short8*)&Bs[rr][(ks ^ ((rr >> 1) & 3)) * 8];
        }
        for (int m = 0; m < 4; m++)
            for (int n = 0; n < 4; n++)
                asm("v_mfma_f32_16x16x32_bf16 %0, %1, %2, %0"
                    : "+v"(acc[m][n]) : "v"(a[m]), "v"(b[n]));
    }

    const int rl = lane & 15;
    const int rbase = wr * 64 + (lane >> 4) * 4;
    for (int m = 0; m < 4; m++) {
        for (int n = 0; n < 4; n++) {
            int col = col0 + wc * 64 + n * 16 + rl;
            float bi = bias[col];
            for (int r = 0; r < 4; r++) {
                long row = row0 + rbase + m * 16 + r;
                float v = acc[m][n][r] + bi;
                if (resid) v += resid[row * D + col];
                C[row * D + col] = v;
            }
        }
    }
}

// ---------------- degree / count kernels ----------------
__global__ void count_inc_kernel(const int* __restrict__ nidx, const int* __restrict__ hidx,
                                 int* cnt_n, int* cnt_h) {
    int i = blockIdx.x * 256 + threadIdx.x;
    if (i < N_INC) {
        atomicAdd(&cnt_h[hidx[i]], 1);
        atomicAdd(&cnt_n[nidx[i]], 1);
    }
}

__global__ void count_batch_kernel(const int* __restrict__ batch, int* gcnt) {
    int i = blockIdx.x * 256 + threadIdx.x;
    if (i < N_NODES) atomicAdd(&gcnt[batch[i]], 1);
}

// ---------------- weight transpose+convert: W[K,512] f32 -> Wt[512,Kpad] bf16 (zero pad) ----------------
__global__ void wtrans_kernel(const float* __restrict__ W, short* __restrict__ Wt, int K, int Kpad) {
    int n = blockIdx.x;  // 0..511
    for (int k = threadIdx.x; k < Kpad; k += 64)
        Wt[(long)n * Kpad + k] = (k < K) ? f2bf(W[(long)k * D + n]) : (short)0;
}

// node_features [N,49] f32 -> A0 [NPAD,64] bf16 (zero pad)
__global__ void cvt_in_kernel(const float* __restrict__ nf, short* __restrict__ A0) {
    int r = blockIdx.x;
    int c = threadIdx.x;
    short v = 0;
    if (r < N_NODES && c < D_IN) v = f2bf(nf[(long)r * D_IN + c]);
    A0[(long)r * KPAD_IN + c] = v;
}

// f32 -> bf16, 8 elems/thread
__global__ void cvt_bf16_kernel(const float* __restrict__ src, short* __restrict__ dst) {
    long i = ((long)blockIdx.x * 256 + threadIdx.x) * 8;
    float4 f0 = *(const float4*)(src + i);
    float4 f1 = *(const float4*)(src + i + 4);
    short8 o;
    o[0] = f2bf(f0.x); o[1] = f2bf(f0.y); o[2] = f2bf(f0.z); o[3] = f2bf(f0.w);
    o[4] = f2bf(f1.x); o[5] = f2bf(f1.y); o[6] = f2bf(f1.z); o[7] = f2bf(f1.w);
    *(short8*)(dst + i) = o;
}

// row-scaled f32 -> bf16: dst[r,:] = bf16(src[r,:] / max(cnt[r],1))
__global__ void cvt_scaled_kernel(const float* __restrict__ src, const int* __restrict__ cnt,
                                  short* __restrict__ dst) {
    int r = blockIdx.x;
    float inv = 1.0f / fmaxf((float)cnt[r], 1.0f);
    long base = (long)r * D + threadIdx.x * 8;
    float4 f0 = *(const float4*)(src + base);
    float4 f1 = *(const float4*)(src + base + 4);
    short8 o;
    o[0] = f2bf(f0.x * inv); o[1] = f2bf(f0.y * inv); o[2] = f2bf(f0.z * inv); o[3] = f2bf(f0.w * inv);
    o[4] = f2bf(f1.x * inv); o[5] = f2bf(f1.y * inv); o[6] = f2bf(f1.z * inv); o[7] = f2bf(f1.w * inv);
    *(short8*)(dst + base) = o;
}

// dst[didx[e],:] += src[sidx[e],:]  — one block (128 thr) per incidence
__global__ void scatter_kernel(const float* __restrict__ src, const int* __restrict__ sidx,
                               const int* __restrict__ didx, float* __restrict__ dst) {
    int e = blockIdx.x;
    int s  = sidx[e];
    int d2 = didx[e];
    float4 v = *(const float4*)(src + (long)s * D + threadIdx.x * 4);
    float* dp = dst + (long)d2 * D + threadIdx.x * 4;
    atomicAdd(dp + 0, v.x);
    atomicAdd(dp + 1, v.y);
    atomicAdd(dp + 2, v.z);
    atomicAdd(dp + 3, v.w);
}

// h[e,:] = h[e,:]/max(deg,1) + type_emb[type[e],:]
__global__ void hedge_msg_kernel(float* __restrict__ h, const int* __restrict__ cnt_h,
                                 const int* __restrict__ types, const float* __restrict__ temb) {
    int e = blockIdx.x;
    float inv = 1.0f / fmaxf((float)cnt_h[e], 1.0f);
    int ty = types[e];
    long base = (long)e * D + threadIdx.x * 4;
    float4 v = *(const float4*)(h + base);
    float4 t = *(const float4*)(temb + (long)ty * D + threadIdx.x * 4);
    v.x = v.x * inv + t.x; v.y = v.y * inv + t.y;
    v.z = v.z * inv + t.z; v.w = v.w * inv + t.w;
    *(float4*)(h + base) = v;
}

// LayerNorm + exact GELU per row
__global__ __launch_bounds__(256) void ln_gelu_kernel(const float* __restrict__ in, float* __restrict__ out,
                                                      const float* __restrict__ g, const float* __restrict__ b) {
    int r = blockIdx.x;
    int t = threadIdx.x;
    const float* ip = in + (long)r * D;
    float v0 = ip[t], v1 = ip[t + 256];
    float s = v0 + v1;
    float q = v0 * v0 + v1 * v1;
    for (int o = 32; o > 0; o >>= 1) {
        s += __shfl_xor(s, o, 64);
        q += __shfl_xor(q, o, 64);
    }
    __shared__ float rs[4], rq[4];
    int w = t >> 6;
    if ((t & 63) == 0) { rs[w] = s; rq[w] = q; }
    __syncthreads();
    s = rs[0] + rs[1] + rs[2] + rs[3];
    q = rq[0] + rq[1] + rq[2] + rq[3];
    float mean = s * (1.0f / D);
    float var  = q * (1.0f / D) - mean * mean;
    float rstd = rsqrtf(var + 1e-5f);
    float y0 = (v0 - mean) * rstd * g[t]       + b[t];
    float y1 = (v1 - mean) * rstd * g[t + 256] + b[t + 256];
    out[(long)r * D + t]       = 0.5f * y0 * (1.0f + erff(y0 * 0.70710678118654752f));
    out[(long)r * D + t + 256] = 0.5f * y1 * (1.0f + erff(y1 * 0.70710678118654752f));
}

// graph pooling: gsum[batch[r],:] += x[r,:]; also emit batch as float
__global__ void pool_kernel(const float* __restrict__ x, const int* __restrict__ batch,
                            float* __restrict__ gsum, float* __restrict__ obatch) {
    int r = blockIdx.x;
    int g = batch[r];
    if (threadIdx.x == 0) obatch[r] = (float)g;
    float4 v = *(const float4*)(x + (long)r * D + threadIdx.x * 4);
    float* gp = gsum + (long)g * D + threadIdx.x * 4;
    atomicAdd(gp + 0, v.x);
    atomicAdd(gp + 1, v.y);
    atomicAdd(gp + 2, v.z);
    atomicAdd(gp + 3, v.w);
}

extern "C" void kernel_launch(void* const* d_in, const int* in_sizes, int n_in,
                              void* d_out, int out_size, void* d_ws, size_t ws_size,
                              hipStream_t stream) {
    (void)in_sizes; (void)n_in; (void)out_size; (void)ws_size;
    const float* nf    = (const float*)d_in[0];
    const int*   nidx  = (const int*)d_in[1];
    const int*   hidx  = (const int*)d_in[2];
    const int*   htype = (const int*)d_in[3];
    const int*   batch = (const int*)d_in[4];
    const float* in_w  = (const float*)d_in[6];
    const float* in_b  = (const float*)d_in[7];
    const float* temb  = (const float*)d_in[8];
    const float* l1w   = (const float*)d_in[9];
    const float* l1b   = (const float*)d_in[10];
    const float* l2w   = (const float*)d_in[11];
    const float* l2b   = (const float*)d_in[12];
    const float* lng   = (const float*)d_in[13];
    const float* lnb   = (const float*)d_in[14];
    const float* outw  = (const float*)d_in[15];
    const float* outb  = (const float*)d_in[16];

    float* out_graph = (float*)d_out;                       // [1024,512]
    float* out_nodes = out_graph + (long)N_GRAPHS * D;      // [100000,512]
    float* out_batch = out_nodes + (long)N_NODES * D;       // [100000]

    char* wsb = (char*)d_ws;
    size_t off = 0;
    auto alloc = [&](size_t bytes) {
        void* p = wsb + off;
        off += (bytes + 255) & ~(size_t)255;
        return p;
    };
    short* A_bf = (short*)alloc((size_t)NPAD * D * 2);
    float* x    = (float*)alloc((size_t)NPAD * D * 4);
    float* t1   = (float*)alloc((size_t)NPAD * D * 4);
    float* h    = (float*)alloc((size_t)N_HEDGES * D * 4);
    float* gsum = (float*)alloc((size_t)N_GRAPHS * D * 4);
    short* G_bf = (short*)alloc((size_t)N_GRAPHS * D * 2);
    short* A0   = (short*)alloc((size_t)NPAD * KPAD_IN * 2);
    short* wt   = (short*)alloc((size_t)D * D * 2);
    int* cnt_h  = (int*)alloc((size_t)N_HEDGES * 4);
    int* cnt_n  = (int*)alloc((size_t)NPAD * 4);
    int* gcnt   = (int*)alloc((size_t)N_GRAPHS * 4);

    // degrees (recomputed every call; ws is not trustworthy across calls)
    hipMemsetAsync(cnt_h, 0, (size_t)N_HEDGES * 4, stream);
    hipMemsetAsync(cnt_n, 0, (size_t)NPAD * 4, stream);
    hipMemsetAsync(gcnt,  0, (size_t)N_GRAPHS * 4, stream);
    count_inc_kernel<<<(N_INC + 255) / 256, 256, 0, stream>>>(nidx, hidx, cnt_n, cnt_h);
    count_batch_kernel<<<(N_NODES + 255) / 256, 256, 0, stream>>>(batch, gcnt);

    // input projection: x = nf @ in_w + in_b
    wtrans_kernel<<<D, 64, 0, stream>>>(in_w, wt, D_IN, KPAD_IN);
    cvt_in_kernel<<<NPAD, 64, 0, stream>>>(nf, A0);
    dim3 gg(NPAD / 128, D / 128);
    gemm_bf16<<<gg, 256, 0, stream>>>(A0, wt, in_b, nullptr, x, KPAD_IN);

    const int cvt_blocks = (int)(((long)NPAD * D / 8) / 256);  // exact
    for (int i = 0; i < 3; i++) {
        // x_trans = x @ l1_w[i] + l1_b[i]
        cvt_bf16_kernel<<<cvt_blocks, 256, 0, stream>>>(x, A_bf);
        wtrans_kernel<<<D, 64, 0, stream>>>(l1w + (size_t)i * D * D, wt, D, D);
        gemm_bf16<<<gg, 256, 0, stream>>>(A_bf, wt, l1b + i * D, nullptr, t1, D);
        // hedge_aggr
        hipMemsetAsync(h, 0, (size_t)N_HEDGES * D * 4, stream);
        scatter_kernel<<<N_INC, 128, 0, stream>>>(t1, nidx, hidx, h);
        // hedge_msg
        hedge_msg_kernel<<<N_HEDGES, 128, 0, stream>>>(h, cnt_h, htype, temb);
        // node_aggr
        hipMemsetAsync(t1, 0, (size_t)NPAD * D * 4, stream);
        scatter_kernel<<<N_INC, 128, 0, stream>>>(h, hidx, nidx, t1);
        cvt_scaled_kernel<<<NPAD, 64, 0, stream>>>(t1, cnt_n, A_bf);
        // out = x + node_aggr @ l2_w[i] + l2_b[i]; then LN + GELU
        wtrans_kernel<<<D, 64, 0, stream>>>(l2w + (size_t)i * D * D, wt, D, D);
        gemm_bf16<<<gg, 256, 0, stream>>>(A_bf, wt, l2b + i * D, x, t1, D);
        ln_gelu_kernel<<<N_NODES, 256, 0, stream>>>(t1, (i < 2) ? x : out_nodes,
                                                    lng + i * D, lnb + i * D);
    }

    // graph pooling + output projection
    hipMemsetAsync(gsum, 0, (size_t)N_GRAPHS * D * 4, stream);
    pool_kernel<<<N_NODES, 128, 0, stream>>>(out_nodes, batch, gsum, out_batch);
    cvt_scaled_kernel<<<N_GRAPHS, 64, 0, stream>>>(gsum, gcnt, G_bf);
    wtrans_kernel<<<D, 64, 0, stream>>>(outw, wt, D, D);
    dim3 gf(N_GRAPHS / 128, D / 128);
    gemm_bf16<<<gf, 256, 0, stream>>>(G_bf, wt, outb, nullptr, out_graph, D);
}

// Round 2
// 2591.329 us; speedup vs baseline: 5.6575x; 5.6575x over previous
//
#include <hip/hip_runtime.h>
#include <math.h>

#define N_NODES  100000
#define N_HEDGES 50000
#define N_INC    300000
#define N_GRAPHS 1024
#define D_IN     49
#define D        512
#define NPAD     100096   // 782 * 128
#define KPAD_IN  64

typedef __attribute__((ext_vector_type(8))) short short8;
typedef __attribute__((ext_vector_type(4))) float f32x4;

__device__ inline short f2bf(float f) {
    union { float f; unsigned u; } v; v.f = f;
    unsigned r = v.u + 0x7fffu + ((v.u >> 16) & 1u);
    return (short)(r >> 16);
}

// ---------------- GEMM: C[M,512] = A[M,K](bf16) @ Bt[512,K](bf16) + bias (+resid) ----------------
// 128x128 tile, 4 waves (2x2), each wave 64x64 via 4x4 of 16x16x32 MFMA.
// Optional bf16 shadow output Cbf.
__global__ __launch_bounds__(256) void gemm_bf16(
    const short* __restrict__ A, const short* __restrict__ Bt,
    const float* __restrict__ bias, const float* __restrict__ resid,
    float* __restrict__ C, short* __restrict__ Cbf, int K)
{
    __shared__ short As[128][32];
    __shared__ short Bs[128][32];
    const int tid  = threadIdx.x;
    const int lane = tid & 63;
    const int wave = tid >> 6;
    const int wr = wave >> 1, wc = wave & 1;
    const long row0 = (long)blockIdx.x * 128;
    const int  col0 = blockIdx.y * 128;

    f32x4 acc[4][4];
    for (int m = 0; m < 4; m++)
        for (int n = 0; n < 4; n++)
            acc[m][n] = (f32x4)(0.0f);

    const int sr = tid >> 1;        // staging row 0..127
    const int s0 = (tid & 1) * 2;   // logical 16B slot 0 or 2
    const int sw = (sr >> 1) & 3;   // XOR swizzle for bank-conflict-free ds_read_b128

    const short* aRow = A  + (row0 + sr) * (long)K;
    const short* bRow = Bt + (long)(col0 + sr) * K;

    for (int k0 = 0; k0 < K; k0 += 32) {
        short8 av0 = *(const short8*)(aRow + k0 + s0 * 8);
        short8 av1 = *(const short8*)(aRow + k0 + s0 * 8 + 8);
        short8 bv0 = *(const short8*)(bRow + k0 + s0 * 8);
        short8 bv1 = *(const short8*)(bRow + k0 + s0 * 8 + 8);
        __syncthreads();
        *(short8*)&As[sr][( s0      ^ sw) * 8] = av0;
        *(short8*)&As[sr][((s0 + 1) ^ sw) * 8] = av1;
        *(short8*)&Bs[sr][( s0      ^ sw) * 8] = bv0;
        *(short8*)&Bs[sr][((s0 + 1) ^ sw) * 8] = bv1;
        __syncthreads();
        const int ks = lane >> 4;
        const int rl = lane & 15;
        short8 a[4], b[4];
        for (int m = 0; m < 4; m++) {
            int rr = wr * 64 + m * 16 + rl;
            a[m] = *(const short8*)&As[rr][(ks ^ ((rr >> 1) & 3)) * 8];
        }
        for (int n = 0; n < 4; n++) {
            int rr = wc * 64 + n * 16 + rl;
            b[n] = *(const short8*)&Bs[rr][(ks ^ ((rr >> 1) & 3)) * 8];
        }
        for (int m = 0; m < 4; m++)
            for (int n = 0; n < 4; n++)
                asm("v_mfma_f32_16x16x32_bf16 %0, %1, %2, %0"
                    : "+v"(acc[m][n]) : "v"(a[m]), "v"(b[n]));
    }

    const int rl = lane & 15;
    const int rbase = wr * 64 + (lane >> 4) * 4;
    for (int m = 0; m < 4; m++) {
        for (int n = 0; n < 4; n++) {
            int col = col0 + wc * 64 + n * 16 + rl;
            float bi = bias[col];
            for (int r = 0; r < 4; r++) {
                long row = row0 + rbase + m * 16 + r;
                float v = acc[m][n][r] + bi;
                if (resid) v += resid[row * D + col];
                C[row * D + col] = v;
                if (Cbf) Cbf[row * D + col] = f2bf(v);
            }
        }
    }
}

// ---------------- degree counts ----------------
__global__ void count_inc_kernel(const int* __restrict__ nidx, const int* __restrict__ hidx,
                                 int* cnt_n, int* cnt_h) {
    int i = blockIdx.x * 256 + threadIdx.x;
    if (i < N_INC) {
        atomicAdd(&cnt_h[hidx[i]], 1);
        atomicAdd(&cnt_n[nidx[i]], 1);
    }
}

// single-block exclusive scan: off[0..n-1] = exclusive prefix of cnt, off[n] = total
__global__ __launch_bounds__(256) void scan_kernel(const int* __restrict__ cnt, int* __restrict__ off, int n) {
    __shared__ int sums[256];
    int t = threadIdx.x;
    int chunk = (n + 255) / 256;
    int s = t * chunk;
    int e = min(s + chunk, n);
    int loc = 0;
    for (int i = s; i < e; i++) loc += cnt[i];
    sums[t] = loc;
    __syncthreads();
    for (int ofs = 1; ofs < 256; ofs <<= 1) {
        int v = (t >= ofs) ? sums[t - ofs] : 0;
        __syncthreads();
        sums[t] += v;
        __syncthreads();
    }
    int run = (t == 0) ? 0 : sums[t - 1];
    for (int i = s; i < e; i++) { off[i] = run; run += cnt[i]; }
    if (t == 255) off[n] = run;
}

// CSR placement via atomic cursors (within-segment order nondeterministic; FP-tolerance OK)
__global__ void place_kernel(const int* __restrict__ nidx, const int* __restrict__ hidx,
                             const int* __restrict__ hoff, const int* __restrict__ noff,
                             int* hcur, int* ncur, int* __restrict__ hlist, int* __restrict__ nlist) {
    int e = blockIdx.x * 256 + threadIdx.x;
    if (e < N_INC) {
        int h = hidx[e], n = nidx[e];
        int p = atomicAdd(&hcur[h], 1);
        hlist[hoff[h] + p] = n;
        int q = atomicAdd(&ncur[n], 1);
        nlist[noff[n] + q] = h;
    }
}

// ---------------- weight transpose+convert: W[K,512] f32 -> Wt[512,Kpad] bf16 ----------------
__global__ void wtrans_kernel(const float* __restrict__ W, short* __restrict__ Wt, int K, int Kpad) {
    int n = blockIdx.x;
    for (int k = threadIdx.x; k < Kpad; k += 64)
        Wt[(long)n * Kpad + k] = (k < K) ? f2bf(W[(long)k * D + n]) : (short)0;
}

// node_features [N,49] f32 -> A0 [NPAD,64] bf16 (zero pad)
__global__ void cvt_in_kernel(const float* __restrict__ nf, short* __restrict__ A0) {
    int r = blockIdx.x;
    int c = threadIdx.x;
    short v = 0;
    if (r < N_NODES && c < D_IN) v = f2bf(nf[(long)r * D_IN + c]);
    A0[(long)r * KPAD_IN + c] = v;
}

// hedge gather + msg: h[e,:] = (sum_j src[hlist[j],:]) / max(deg,1) + temb[type[e],:]
__global__ __launch_bounds__(256) void hedge_gather_kernel(
    const float* __restrict__ src, const int* __restrict__ hoff, const int* __restrict__ hlist,
    const int* __restrict__ htype, const float* __restrict__ temb, float* __restrict__ out)
{
    int hrow = blockIdx.x * 4 + (threadIdx.x >> 6);
    if (hrow >= N_HEDGES) return;
    int lane = threadIdx.x & 63;
    int s = hoff[hrow], e = hoff[hrow + 1];
    float acc[8] = {0, 0, 0, 0, 0, 0, 0, 0};
    for (int j = s; j < e; j++) {
        const float* rp = src + (long)hlist[j] * D + lane * 8;
        float4 v0 = *(const float4*)rp;
        float4 v1 = *(const float4*)(rp + 4);
        acc[0] += v0.x; acc[1] += v0.y; acc[2] += v0.z; acc[3] += v0.w;
        acc[4] += v1.x; acc[5] += v1.y; acc[6] += v1.z; acc[7] += v1.w;
    }
    float inv = 1.0f / fmaxf((float)(e - s), 1.0f);
    const float* tp = temb + (long)htype[hrow] * D + lane * 8;
    float4 t0 = *(const float4*)tp;
    float4 t1 = *(const float4*)(tp + 4);
    float* op = out + (long)hrow * D + lane * 8;
    float4 o0, o1;
    o0.x = acc[0] * inv + t0.x; o0.y = acc[1] * inv + t0.y;
    o0.z = acc[2] * inv + t0.z; o0.w = acc[3] * inv + t0.w;
    o1.x = acc[4] * inv + t1.x; o1.y = acc[5] * inv + t1.y;
    o1.z = acc[6] * inv + t1.z; o1.w = acc[7] * inv + t1.w;
    *(float4*)op = o0;
    *(float4*)(op + 4) = o1;
}

// node gather: Abf[r,:] = bf16((sum_j hmsg[nlist[j],:]) / max(deg,1)); pad rows zeroed
__global__ __launch_bounds__(256) void node_gather_kernel(
    const float* __restrict__ hmsg, const int* __restrict__ noff, const int* __restrict__ nlist,
    short* __restrict__ Abf)
{
    int r = blockIdx.x * 4 + (threadIdx.x >> 6);
    if (r >= NPAD) return;
    int lane = threadIdx.x & 63;
    short8 o = (short8)0;
    if (r < N_NODES) {
        int s = noff[r], e = noff[r + 1];
        float acc[8] = {0, 0, 0, 0, 0, 0, 0, 0};
        for (int j = s; j < e; j++) {
            const float* rp = hmsg + (long)nlist[j] * D + lane * 8;
            float4 v0 = *(const float4*)rp;
            float4 v1 = *(const float4*)(rp + 4);
            acc[0] += v0.x; acc[1] += v0.y; acc[2] += v0.z; acc[3] += v0.w;
            acc[4] += v1.x; acc[5] += v1.y; acc[6] += v1.z; acc[7] += v1.w;
        }
        float inv = 1.0f / fmaxf((float)(e - s), 1.0f);
        for (int k = 0; k < 8; k++) o[k] = f2bf(acc[k] * inv);
    }
    *(short8*)(Abf + (long)r * D + lane * 8) = o;
}

// LayerNorm + exact GELU per row; optional bf16 shadow output
__global__ __launch_bounds__(256) void ln_gelu_kernel(
    const float* __restrict__ in, float* __restrict__ out, short* __restrict__ outbf,
    const float* __restrict__ g, const float* __restrict__ b)
{
    int r = blockIdx.x;
    int t = threadIdx.x;
    const float* ip = in + (long)r * D;
    float v0 = ip[t], v1 = ip[t + 256];
    float s = v0 + v1;
    float q = v0 * v0 + v1 * v1;
    for (int o = 32; o > 0; o >>= 1) {
        s += __shfl_xor(s, o, 64);
        q += __shfl_xor(q, o, 64);
    }
    __shared__ float rs[4], rq[4];
    int w = t >> 6;
    if ((t & 63) == 0) { rs[w] = s; rq[w] = q; }
    __syncthreads();
    s = rs[0] + rs[1] + rs[2] + rs[3];
    q = rq[0] + rq[1] + rq[2] + rq[3];
    float mean = s * (1.0f / D);
    float var  = q * (1.0f / D) - mean * mean;
    float rstd = rsqrtf(var + 1e-5f);
    float y0 = (v0 - mean) * rstd * g[t]       + b[t];
    float y1 = (v1 - mean) * rstd * g[t + 256] + b[t + 256];
    float g0 = 0.5f * y0 * (1.0f + erff(y0 * 0.70710678118654752f));
    float g1 = 0.5f * y1 * (1.0f + erff(y1 * 0.70710678118654752f));
    out[(long)r * D + t]       = g0;
    out[(long)r * D + t + 256] = g1;
    if (outbf) {
        outbf[(long)r * D + t]       = f2bf(g0);
        outbf[(long)r * D + t + 256] = f2bf(g1);
    }
}

// graph pooling via sorted batch segments: Gbf[g,:] = bf16(mean of x rows in segment g)
__global__ __launch_bounds__(64) void pool_kernel(const float* __restrict__ x, const int* __restrict__ batch,
                                                  short* __restrict__ Gbf) {
    int g = blockIdx.x;
    int lo = 0, hi = N_NODES;
    while (lo < hi) { int mid = (lo + hi) >> 1; if (batch[mid] < g) lo = mid + 1; else hi = mid; }
    int s = lo;
    hi = N_NODES;
    while (lo < hi) { int mid = (lo + hi) >> 1; if (batch[mid] < g + 1) lo = mid + 1; else hi = mid; }
    int e = lo;
    int lane = threadIdx.x;
    float acc[8] = {0, 0, 0, 0, 0, 0, 0, 0};
    for (int r = s; r < e; r++) {
        const float* rp = x + (long)r * D + lane * 8;
        float4 v0 = *(const float4*)rp;
        float4 v1 = *(const float4*)(rp + 4);
        acc[0] += v0.x; acc[1] += v0.y; acc[2] += v0.z; acc[3] += v0.w;
        acc[4] += v1.x; acc[5] += v1.y; acc[6] += v1.z; acc[7] += v1.w;
    }
    float inv = 1.0f / fmaxf((float)(e - s), 1.0f);
    short8 o;
    for (int k = 0; k < 8; k++) o[k] = f2bf(acc[k] * inv);
    *(short8*)(Gbf + (long)g * D + lane * 8) = o;
}

__global__ void batchf_kernel(const int* __restrict__ batch, float* __restrict__ ob) {
    int i = blockIdx.x * 256 + threadIdx.x;
    if (i < N_NODES) ob[i] = (float)batch[i];
}

extern "C" void kernel_launch(void* const* d_in, const int* in_sizes, int n_in,
                              void* d_out, int out_size, void* d_ws, size_t ws_size,
                              hipStream_t stream) {
    (void)in_sizes; (void)n_in; (void)out_size; (void)ws_size;
    const float* nf    = (const float*)d_in[0];
    const int*   nidx  = (const int*)d_in[1];
    const int*   hidx  = (const int*)d_in[2];
    const int*   htype = (const int*)d_in[3];
    const int*   batch = (const int*)d_in[4];
    const float* in_w  = (const float*)d_in[6];
    const float* in_b  = (const float*)d_in[7];
    const float* temb  = (const float*)d_in[8];
    const float* l1w   = (const float*)d_in[9];
    const float* l1b   = (const float*)d_in[10];
    const float* l2w   = (const float*)d_in[11];
    const float* l2b   = (const float*)d_in[12];
    const float* lng   = (const float*)d_in[13];
    const float* lnb   = (const float*)d_in[14];
    const float* outw  = (const float*)d_in[15];
    const float* outb  = (const float*)d_in[16];

    float* out_graph = (float*)d_out;                       // [1024,512]
    float* out_nodes = out_graph + (long)N_GRAPHS * D;      // [100000,512]
    float* out_batch = out_nodes + (long)N_NODES * D;       // [100000]

    char* wsb = (char*)d_ws;
    size_t off = 0;
    auto alloc = [&](size_t bytes) {
        void* p = wsb + off;
        off += (bytes + 255) & ~(size_t)255;
        return p;
    };
    short* A_bf  = (short*)alloc((size_t)NPAD * D * 2);
    float* x     = (float*)alloc((size_t)NPAD * D * 4);
    float* t1    = (float*)alloc((size_t)NPAD * D * 4);
    float* h     = (float*)alloc((size_t)N_HEDGES * D * 4);
    short* G_bf  = (short*)alloc((size_t)N_GRAPHS * D * 2);
    short* A0    = (short*)alloc((size_t)NPAD * KPAD_IN * 2);
    short* wt    = (short*)alloc((size_t)D * D * 2);
    int* cnt_h   = (int*)alloc((size_t)N_HEDGES * 4);
    int* cnt_n   = (int*)alloc((size_t)N_NODES * 4);
    int* hoff    = (int*)alloc((size_t)(N_HEDGES + 1) * 4);
    int* noff    = (int*)alloc((size_t)(N_NODES + 1) * 4);
    int* hcur    = (int*)alloc((size_t)N_HEDGES * 4);
    int* ncur    = (int*)alloc((size_t)N_NODES * 4);
    int* hlist   = (int*)alloc((size_t)N_INC * 4);
    int* nlist   = (int*)alloc((size_t)N_INC * 4);

    // ---- build CSR (both directions) ----
    hipMemsetAsync(cnt_h, 0, (size_t)N_HEDGES * 4, stream);
    hipMemsetAsync(cnt_n, 0, (size_t)N_NODES * 4, stream);
    hipMemsetAsync(hcur,  0, (size_t)N_HEDGES * 4, stream);
    hipMemsetAsync(ncur,  0, (size_t)N_NODES * 4, stream);
    count_inc_kernel<<<(N_INC + 255) / 256, 256, 0, stream>>>(nidx, hidx, cnt_n, cnt_h);
    scan_kernel<<<1, 256, 0, stream>>>(cnt_h, hoff, N_HEDGES);
    scan_kernel<<<1, 256, 0, stream>>>(cnt_n, noff, N_NODES);
    place_kernel<<<(N_INC + 255) / 256, 256, 0, stream>>>(nidx, hidx, hoff, noff, hcur, ncur, hlist, nlist);
    batchf_kernel<<<(N_NODES + 255) / 256, 256, 0, stream>>>(batch, out_batch);

    // ---- input projection: x = nf @ in_w + in_b (+ bf16 shadow for layer-0 l1 GEMM) ----
    wtrans_kernel<<<D, 64, 0, stream>>>(in_w, wt, D_IN, KPAD_IN);
    cvt_in_kernel<<<NPAD, 64, 0, stream>>>(nf, A0);
    dim3 gg(NPAD / 128, D / 128);
    gemm_bf16<<<gg, 256, 0, stream>>>(A0, wt, in_b, nullptr, x, A_bf, KPAD_IN);

    for (int i = 0; i < 3; i++) {
        // x_trans = x @ l1_w[i] + l1_b[i]
        wtrans_kernel<<<D, 64, 0, stream>>>(l1w + (size_t)i * D * D, wt, D, D);
        gemm_bf16<<<gg, 256, 0, stream>>>(A_bf, wt, l1b + i * D, nullptr, t1, nullptr, D);
        // hedge_aggr / deg + type_emb  (gather)
        hedge_gather_kernel<<<(N_HEDGES + 3) / 4, 256, 0, stream>>>(t1, hoff, hlist, htype, temb, h);
        // node_aggr / deg -> bf16      (gather)
        node_gather_kernel<<<(NPAD + 3) / 4, 256, 0, stream>>>(h, noff, nlist, A_bf);
        // out = x + node_aggr @ l2_w[i] + l2_b[i]; then LN + GELU (+ bf16 shadow)
        wtrans_kernel<<<D, 64, 0, stream>>>(l2w + (size_t)i * D * D, wt, D, D);
        gemm_bf16<<<gg, 256, 0, stream>>>(A_bf, wt, l2b + i * D, x, t1, nullptr, D);
        ln_gelu_kernel<<<N_NODES, 256, 0, stream>>>(t1, (i < 2) ? x : out_nodes,
                                                    (i < 2) ? A_bf : nullptr,
                                                    lng + i * D, lnb + i * D);
    }

    // ---- graph pooling (sorted-batch segments) + output projection ----
    pool_kernel<<<N_GRAPHS, 64, 0, stream>>>(out_nodes, batch, G_bf);
    wtrans_kernel<<<D, 64, 0, stream>>>(outw, wt, D, D);
    dim3 gf(N_GRAPHS / 128, D / 128);
    gemm_bf16<<<gf, 256, 0, stream>>>(G_bf, wt, outb, nullptr, out_graph, nullptr, D);
}

// Round 3
// 1836.357 us; speedup vs baseline: 7.9834x; 1.4111x over previous
//
#include <hip/hip_runtime.h>
#include <math.h>

#define N_NODES  100000
#define N_HEDGES 50000
#define N_INC    300000
#define N_GRAPHS 1024
#define D_IN     49
#define D        512
#define NPAD     100096   // 782 * 128
#define KPAD_IN  64

typedef __attribute__((ext_vector_type(8))) short short8;
typedef __attribute__((ext_vector_type(4))) float f32x4;

__device__ __forceinline__ short f2bf(float f) {
    union { float f; unsigned u; } v; v.f = f;
    unsigned r = v.u + 0x7fffu + ((v.u >> 16) & 1u);
    return (short)(r >> 16);
}
__device__ __forceinline__ float bf2f(short s) {
    union { unsigned u; float f; } v; v.u = ((unsigned)(unsigned short)s) << 16;
    return v.f;
}

// ---------------- GEMM: C[M,512] = A[M,K](bf16) @ Bt[512,K](bf16) + bias (+resid_bf16) ----------------
// 128x128 tile, 4 waves (2x2), 2-phase pipeline: reg-staged prefetch + LDS double buffer,
// ONE barrier per 32-K step. Linear LDS (64B rows) = min-phase conflict-free b128 access.
__global__ __launch_bounds__(256) void gemm_bf16(
    const short* __restrict__ A, const short* __restrict__ Bt,
    const float* __restrict__ bias, const short* __restrict__ residbf,
    short* __restrict__ Cbf, float* __restrict__ Cf, int K, int nby)
{
    __shared__ short As[2][128][32];
    __shared__ short Bs[2][128][32];
    const int tid  = threadIdx.x;
    const int lane = tid & 63;
    const int wave = tid >> 6;
    const int wr = wave >> 1, wc = wave & 1;

    // bijective XCD-aware swizzle (m204)
    const int nwg = gridDim.x;
    const int q = nwg >> 3, r = nwg & 7;
    const int xcd = blockIdx.x & 7, loc = blockIdx.x >> 3;
    const int wg = (xcd < r) ? (xcd * (q + 1) + loc) : (r * (q + 1) + (xcd - r) * q + loc);
    const long row0 = (long)(wg / nby) * 128;
    const int  col0 = (wg % nby) * 128;

    f32x4 acc[4][4];
    #pragma unroll
    for (int m = 0; m < 4; m++)
        #pragma unroll
        for (int n = 0; n < 4; n++)
            acc[m][n] = (f32x4)(0.0f);

    const int srow = tid >> 2;      // 0..63
    const int slot = tid & 3;       // 16B slot in 64B row
    const short* aP = A  + (row0 + srow) * (long)K + slot * 8;
    const short* bP = Bt + ((long)col0 + srow) * K + slot * 8;
    const long rstep = 64 * (long)K;

    // prologue: tile 0 -> regs -> LDS buf 0
    short8 ra0 = *(const short8*)(aP);
    short8 ra1 = *(const short8*)(aP + rstep);
    short8 rb0 = *(const short8*)(bP);
    short8 rb1 = *(const short8*)(bP + rstep);
    *(short8*)&As[0][srow][slot * 8]      = ra0;
    *(short8*)&As[0][64 + srow][slot * 8] = ra1;
    *(short8*)&Bs[0][srow][slot * 8]      = rb0;
    *(short8*)&Bs[0][64 + srow][slot * 8] = rb1;

    const int ks = lane >> 4;
    const int rl = lane & 15;
    int cur = 0;
    const int nk = K >> 5;
    for (int t = 0; t < nk; t++) {
        if (t + 1 < nk) {                       // issue next-tile loads early (latency hides under MFMA)
            const short* ap = aP + (t + 1) * 32;
            const short* bp = bP + (t + 1) * 32;
            ra0 = *(const short8*)(ap);
            ra1 = *(const short8*)(ap + rstep);
            rb0 = *(const short8*)(bp);
            rb1 = *(const short8*)(bp + rstep);
        }
        __syncthreads();                        // buf[cur] visible; prev reads drained
        short8 a[4], b[4];
        #pragma unroll
        for (int m = 0; m < 4; m++)
            a[m] = *(const short8*)&As[cur][wr * 64 + m * 16 + rl][ks * 8];
        #pragma unroll
        for (int n = 0; n < 4; n++)
            b[n] = *(const short8*)&Bs[cur][wc * 64 + n * 16 + rl][ks * 8];
        #pragma unroll
        for (int m = 0; m < 4; m++)
            #pragma unroll
            for (int n = 0; n < 4; n++)
                asm("v_mfma_f32_16x16x32_bf16 %0, %1, %2, %0"
                    : "+v"(acc[m][n]) : "v"(a[m]), "v"(b[n]));
        if (t + 1 < nk) {                       // write next tile into the OTHER buffer
            const int nxt = cur ^ 1;
            *(short8*)&As[nxt][srow][slot * 8]      = ra0;
            *(short8*)&As[nxt][64 + srow][slot * 8] = ra1;
            *(short8*)&Bs[nxt][srow][slot * 8]      = rb0;
            *(short8*)&Bs[nxt][64 + srow][slot * 8] = rb1;
            cur = nxt;
        }
    }

    const int rl2 = lane & 15;
    const int rb4 = wr * 64 + (lane >> 4) * 4;
    #pragma unroll
    for (int m = 0; m < 4; m++) {
        #pragma unroll
        for (int n = 0; n < 4; n++) {
            const int col = col0 + wc * 64 + n * 16 + rl2;
            const float bi = bias[col];
            #pragma unroll
            for (int rr = 0; rr < 4; rr++) {
                const long row = row0 + rb4 + m * 16 + rr;
                float v = acc[m][n][rr] + bi;
                if (residbf) v += bf2f(residbf[row * D + col]);
                if (Cbf) Cbf[row * D + col] = f2bf(v);
                if (Cf)  Cf[row * D + col]  = v;
            }
        }
    }
}

// ---------------- degree counts ----------------
__global__ void count_inc_kernel(const int* __restrict__ nidx, const int* __restrict__ hidx,
                                 int* cnt_n, int* cnt_h) {
    int i = blockIdx.x * 256 + threadIdx.x;
    if (i < N_INC) {
        atomicAdd(&cnt_h[hidx[i]], 1);
        atomicAdd(&cnt_n[nidx[i]], 1);
    }
}

// single-block exclusive scan
__global__ __launch_bounds__(256) void scan_kernel(const int* __restrict__ cnt, int* __restrict__ off, int n) {
    __shared__ int sums[256];
    int t = threadIdx.x;
    int chunk = (n + 255) / 256;
    int s = t * chunk;
    int e = min(s + chunk, n);
    int loc = 0;
    for (int i = s; i < e; i++) loc += cnt[i];
    sums[t] = loc;
    __syncthreads();
    for (int ofs = 1; ofs < 256; ofs <<= 1) {
        int v = (t >= ofs) ? sums[t - ofs] : 0;
        __syncthreads();
        sums[t] += v;
        __syncthreads();
    }
    int run = (t == 0) ? 0 : sums[t - 1];
    for (int i = s; i < e; i++) { off[i] = run; run += cnt[i]; }
    if (t == 255) off[n] = run;
}

// CSR placement via atomic cursors
__global__ void place_kernel(const int* __restrict__ nidx, const int* __restrict__ hidx,
                             const int* __restrict__ hoff, const int* __restrict__ noff,
                             int* hcur, int* ncur, int* __restrict__ hlist, int* __restrict__ nlist) {
    int e = blockIdx.x * 256 + threadIdx.x;
    if (e < N_INC) {
        int h = hidx[e], n = nidx[e];
        int p = atomicAdd(&hcur[h], 1);
        hlist[hoff[h] + p] = n;
        int q = atomicAdd(&ncur[n], 1);
        nlist[noff[n] + q] = h;
    }
}

// ---------------- weight transpose+convert: W[K,512] f32 -> Wt[512,Kpad] bf16 ----------------
__global__ void wtrans_kernel(const float* __restrict__ W, short* __restrict__ Wt, int K, int Kpad) {
    int n = blockIdx.x;
    for (int k = threadIdx.x; k < Kpad; k += 64)
        Wt[(long)n * Kpad + k] = (k < K) ? f2bf(W[(long)k * D + n]) : (short)0;
}

// node_features [N,49] f32 -> A0 [NPAD,64] bf16 (zero pad)
__global__ void cvt_in_kernel(const float* __restrict__ nf, short* __restrict__ A0) {
    int r = blockIdx.x;
    int c = threadIdx.x;
    short v = 0;
    if (r < N_NODES && c < D_IN) v = f2bf(nf[(long)r * D_IN + c]);
    A0[(long)r * KPAD_IN + c] = v;
}

// hedge gather + msg (bf16 in/out, f32 accum): h[e,:] = (sum src[members]) / deg + temb[type]
__global__ __launch_bounds__(256) void hedge_gather_kernel(
    const short* __restrict__ src, const int* __restrict__ hoff, const int* __restrict__ hlist,
    const int* __restrict__ htype, const float* __restrict__ temb, short* __restrict__ out)
{
    int hrow = blockIdx.x * 4 + (threadIdx.x >> 6);
    if (hrow >= N_HEDGES) return;
    int lane = threadIdx.x & 63;
    int s = hoff[hrow], e = hoff[hrow + 1];
    float acc[8] = {0, 0, 0, 0, 0, 0, 0, 0};
    for (int j = s; j < e; j++) {
        short8 v = *(const short8*)(src + (long)hlist[j] * D + lane * 8);
        #pragma unroll
        for (int k = 0; k < 8; k++) acc[k] += bf2f(v[k]);
    }
    float inv = 1.0f / fmaxf((float)(e - s), 1.0f);
    const float* tp = temb + (long)htype[hrow] * D + lane * 8;
    float4 t0 = *(const float4*)tp;
    float4 t1 = *(const float4*)(tp + 4);
    float tv[8] = {t0.x, t0.y, t0.z, t0.w, t1.x, t1.y, t1.z, t1.w};
    short8 o;
    #pragma unroll
    for (int k = 0; k < 8; k++) o[k] = f2bf(acc[k] * inv + tv[k]);
    *(short8*)(out + (long)hrow * D + lane * 8) = o;
}

// node gather (bf16 in/out): Abf[r,:] = (sum hmsg[edges]) / deg ; pad rows zeroed
__global__ __launch_bounds__(256) void node_gather_kernel(
    const short* __restrict__ hmsg, const int* __restrict__ noff, const int* __restrict__ nlist,
    short* __restrict__ Abf)
{
    int r = blockIdx.x * 4 + (threadIdx.x >> 6);
    if (r >= NPAD) return;
    int lane = threadIdx.x & 63;
    short8 o = (short8)0;
    if (r < N_NODES) {
        int s = noff[r], e = noff[r + 1];
        float acc[8] = {0, 0, 0, 0, 0, 0, 0, 0};
        for (int j = s; j < e; j++) {
            short8 v = *(const short8*)(hmsg + (long)nlist[j] * D + lane * 8);
            #pragma unroll
            for (int k = 0; k < 8; k++) acc[k] += bf2f(v[k]);
        }
        float inv = 1.0f / fmaxf((float)(e - s), 1.0f);
        #pragma unroll
        for (int k = 0; k < 8; k++) o[k] = f2bf(acc[k] * inv);
    }
    *(short8*)(Abf + (long)r * D + lane * 8) = o;
}

// LayerNorm + exact GELU, one wave per row (no LDS/barrier); bf16 in, bf16 out (+opt f32)
__global__ __launch_bounds__(256) void ln_gelu_kernel(
    const short* __restrict__ in, short* __restrict__ outbf, float* __restrict__ outf,
    const float* __restrict__ g, const float* __restrict__ b)
{
    const int row = blockIdx.x * 4 + (threadIdx.x >> 6);   // grid covers exactly N_NODES
    const int lane = threadIdx.x & 63;
    short8 v = *(const short8*)(in + (long)row * D + lane * 8);
    float f[8];
    float s = 0.f, q = 0.f;
    #pragma unroll
    for (int j = 0; j < 8; j++) { f[j] = bf2f(v[j]); s += f[j]; q += f[j] * f[j]; }
    #pragma unroll
    for (int o = 32; o > 0; o >>= 1) { s += __shfl_xor(s, o, 64); q += __shfl_xor(q, o, 64); }
    const float mean = s * (1.0f / D);
    const float var  = q * (1.0f / D) - mean * mean;
    const float rstd = rsqrtf(var + 1e-5f);
    const float4 g0 = *(const float4*)(g + lane * 8);
    const float4 g1 = *(const float4*)(g + lane * 8 + 4);
    const float4 b0 = *(const float4*)(b + lane * 8);
    const float4 b1 = *(const float4*)(b + lane * 8 + 4);
    const float gv[8] = {g0.x, g0.y, g0.z, g0.w, g1.x, g1.y, g1.z, g1.w};
    const float bv[8] = {b0.x, b0.y, b0.z, b0.w, b1.x, b1.y, b1.z, b1.w};
    float yout[8];
    short8 o8;
    #pragma unroll
    for (int j = 0; j < 8; j++) {
        float y = (f[j] - mean) * rstd * gv[j] + bv[j];
        float gl = 0.5f * y * (1.0f + erff(y * 0.70710678118654752f));
        yout[j] = gl;
        o8[j] = f2bf(gl);
    }
    *(short8*)(outbf + (long)row * D + lane * 8) = o8;
    if (outf) {
        float4 o0 = {yout[0], yout[1], yout[2], yout[3]};
        float4 o1 = {yout[4], yout[5], yout[6], yout[7]};
        *(float4*)(outf + (long)row * D + lane * 8) = o0;
        *(float4*)(outf + (long)row * D + lane * 8 + 4) = o1;
    }
}

// graph pooling via sorted batch segments (bf16 in): Gbf[g,:] = bf16(mean of rows)
__global__ __launch_bounds__(64) void pool_kernel(const short* __restrict__ x, const int* __restrict__ batch,
                                                  short* __restrict__ Gbf) {
    int g = blockIdx.x;
    int lo = 0, hi = N_NODES;
    while (lo < hi) { int mid = (lo + hi) >> 1; if (batch[mid] < g) lo = mid + 1; else hi = mid; }
    int s = lo;
    hi = N_NODES;
    while (lo < hi) { int mid = (lo + hi) >> 1; if (batch[mid] < g + 1) lo = mid + 1; else hi = mid; }
    int e = lo;
    int lane = threadIdx.x;
    float acc[8] = {0, 0, 0, 0, 0, 0, 0, 0};
    for (int r = s; r < e; r++) {
        short8 v = *(const short8*)(x + (long)r * D + lane * 8);
        #pragma unroll
        for (int k = 0; k < 8; k++) acc[k] += bf2f(v[k]);
    }
    float inv = 1.0f / fmaxf((float)(e - s), 1.0f);
    short8 o;
    #pragma unroll
    for (int k = 0; k < 8; k++) o[k] = f2bf(acc[k] * inv);
    *(short8*)(Gbf + (long)g * D + lane * 8) = o;
}

__global__ void batchf_kernel(const int* __restrict__ batch, float* __restrict__ ob) {
    int i = blockIdx.x * 256 + threadIdx.x;
    if (i < N_NODES) ob[i] = (float)batch[i];
}

extern "C" void kernel_launch(void* const* d_in, const int* in_sizes, int n_in,
                              void* d_out, int out_size, void* d_ws, size_t ws_size,
                              hipStream_t stream) {
    (void)in_sizes; (void)n_in; (void)out_size; (void)ws_size;
    const float* nf    = (const float*)d_in[0];
    const int*   nidx  = (const int*)d_in[1];
    const int*   hidx  = (const int*)d_in[2];
    const int*   htype = (const int*)d_in[3];
    const int*   batch = (const int*)d_in[4];
    const float* in_w  = (const float*)d_in[6];
    const float* in_b  = (const float*)d_in[7];
    const float* temb  = (const float*)d_in[8];
    const float* l1w   = (const float*)d_in[9];
    const float* l1b   = (const float*)d_in[10];
    const float* l2w   = (const float*)d_in[11];
    const float* l2b   = (const float*)d_in[12];
    const float* lng   = (const float*)d_in[13];
    const float* lnb   = (const float*)d_in[14];
    const float* outw  = (const float*)d_in[15];
    const float* outb  = (const float*)d_in[16];

    float* out_graph = (float*)d_out;                       // [1024,512]
    float* out_nodes = out_graph + (long)N_GRAPHS * D;      // [100000,512]
    float* out_batch = out_nodes + (long)N_NODES * D;       // [100000]

    char* wsb = (char*)d_ws;
    size_t off = 0;
    auto alloc = [&](size_t bytes) {
        void* p = wsb + off;
        off += (bytes + 255) & ~(size_t)255;
        return p;
    };
    short* x_bf  = (short*)alloc((size_t)NPAD * D * 2);
    short* t1_bf = (short*)alloc((size_t)NPAD * D * 2);
    short* A_bf  = (short*)alloc((size_t)NPAD * D * 2);
    short* h_bf  = (short*)alloc((size_t)N_HEDGES * D * 2);
    short* G_bf  = (short*)alloc((size_t)N_GRAPHS * D * 2);
    short* A0    = (short*)alloc((size_t)NPAD * KPAD_IN * 2);
    short* wt    = (short*)alloc((size_t)D * D * 2);
    int* cnt_h   = (int*)alloc((size_t)N_HEDGES * 4);
    int* cnt_n   = (int*)alloc((size_t)N_NODES * 4);
    int* hoff    = (int*)alloc((size_t)(N_HEDGES + 1) * 4);
    int* noff    = (int*)alloc((size_t)(N_NODES + 1) * 4);
    int* hcur    = (int*)alloc((size_t)N_HEDGES * 4);
    int* ncur    = (int*)alloc((size_t)N_NODES * 4);
    int* hlist   = (int*)alloc((size_t)N_INC * 4);
    int* nlist   = (int*)alloc((size_t)N_INC * 4);

    // ---- build CSR (both directions) ----
    hipMemsetAsync(cnt_h, 0, (size_t)N_HEDGES * 4, stream);
    hipMemsetAsync(cnt_n, 0, (size_t)N_NODES * 4, stream);
    hipMemsetAsync(hcur,  0, (size_t)N_HEDGES * 4, stream);
    hipMemsetAsync(ncur,  0, (size_t)N_NODES * 4, stream);
    count_inc_kernel<<<(N_INC + 255) / 256, 256, 0, stream>>>(nidx, hidx, cnt_n, cnt_h);
    scan_kernel<<<1, 256, 0, stream>>>(cnt_h, hoff, N_HEDGES);
    scan_kernel<<<1, 256, 0, stream>>>(cnt_n, noff, N_NODES);
    place_kernel<<<(N_INC + 255) / 256, 256, 0, stream>>>(nidx, hidx, hoff, noff, hcur, ncur, hlist, nlist);
    batchf_kernel<<<(N_NODES + 255) / 256, 256, 0, stream>>>(batch, out_batch);

    // ---- input projection: x_bf = bf16(nf @ in_w + in_b) ----
    wtrans_kernel<<<D, 64, 0, stream>>>(in_w, wt, D_IN, KPAD_IN);
    cvt_in_kernel<<<NPAD, 64, 0, stream>>>(nf, A0);
    const int NWG = (NPAD / 128) * 4;   // 3128
    gemm_bf16<<<NWG, 256, 0, stream>>>(A0, wt, in_b, nullptr, x_bf, nullptr, KPAD_IN, 4);

    for (int i = 0; i < 3; i++) {
        // t1 = x @ l1_w[i] + l1_b[i]
        wtrans_kernel<<<D, 64, 0, stream>>>(l1w + (size_t)i * D * D, wt, D, D);
        gemm_bf16<<<NWG, 256, 0, stream>>>(x_bf, wt, l1b + i * D, nullptr, t1_bf, nullptr, D, 4);
        // hedge aggregate + msg
        hedge_gather_kernel<<<(N_HEDGES + 3) / 4, 256, 0, stream>>>(t1_bf, hoff, hlist, htype, temb, h_bf);
        // node aggregate
        node_gather_kernel<<<NPAD / 4, 256, 0, stream>>>(h_bf, noff, nlist, A_bf);
        // y = x + node_aggr @ l2_w[i] + l2_b[i]
        wtrans_kernel<<<D, 64, 0, stream>>>(l2w + (size_t)i * D * D, wt, D, D);
        gemm_bf16<<<NWG, 256, 0, stream>>>(A_bf, wt, l2b + i * D, x_bf, t1_bf, nullptr, D, 4);
        // x = gelu(ln(y));  final layer also writes f32 out_nodes
        ln_gelu_kernel<<<N_NODES / 4, 256, 0, stream>>>(t1_bf, x_bf, (i < 2) ? nullptr : out_nodes,
                                                        lng + i * D, lnb + i * D);
    }

    // ---- graph pooling + output projection ----
    pool_kernel<<<N_GRAPHS, 64, 0, stream>>>(x_bf, batch, G_bf);
    wtrans_kernel<<<D, 64, 0, stream>>>(outw, wt, D, D);
    gemm_bf16<<<(N_GRAPHS / 128) * 4, 256, 0, stream>>>(G_bf, wt, outb, nullptr, nullptr, out_graph, D, 4);
}